// Round 1
// baseline (283.865 us; speedup 1.0000x reference)
//
#include <hip/hip_runtime.h>

// out[k, n] = dot(x[n, 0:4], W[k, 0:4]) + b[k],  k in [0,32), n in [0, 2e6)
// Memory-bound: 32 MB read + 256 MB write. Each thread handles 4 rows,
// stores one float4 per head (coalesced, 16B/lane).

constexpr int K = 32;
constexpr int D = 4;

__global__ __launch_bounds__(256) void bignet_kernel(
    const float* __restrict__ x,
    const float* __restrict__ W,
    const float* __restrict__ b,
    float* __restrict__ out,
    int n4,        // number of 4-row groups (N/4)
    int N)         // total rows
{
    __shared__ float sW[K * D];
    __shared__ float sb[K];
    const int t = threadIdx.x;
    if (t < K * D) sW[t] = W[t];
    if (t < K)     sb[t] = b[t];
    __syncthreads();

    const int g = blockIdx.x * blockDim.x + t;
    if (g >= n4) return;

    // 4 consecutive rows of x: 64 contiguous bytes per thread.
    const float4* x4 = reinterpret_cast<const float4*>(x);
    const float4 x0 = x4[(size_t)g * 4 + 0];
    const float4 x1 = x4[(size_t)g * 4 + 1];
    const float4 x2 = x4[(size_t)g * 4 + 2];
    const float4 x3 = x4[(size_t)g * 4 + 3];

    #pragma unroll 4
    for (int k = 0; k < K; ++k) {
        const float w0 = sW[k * D + 0];
        const float w1 = sW[k * D + 1];
        const float w2 = sW[k * D + 2];
        const float w3 = sW[k * D + 3];
        const float bk = sb[k];

        float4 o;
        o.x = fmaf(x0.x, w0, fmaf(x0.y, w1, fmaf(x0.z, w2, fmaf(x0.w, w3, bk))));
        o.y = fmaf(x1.x, w0, fmaf(x1.y, w1, fmaf(x1.z, w2, fmaf(x1.w, w3, bk))));
        o.z = fmaf(x2.x, w0, fmaf(x2.y, w1, fmaf(x2.z, w2, fmaf(x2.w, w3, bk))));
        o.w = fmaf(x3.x, w0, fmaf(x3.y, w1, fmaf(x3.z, w2, fmaf(x3.w, w3, bk))));

        // out + k*N is 16B-aligned (k*N*4B = k*8,000,000 B).
        float4* ok = reinterpret_cast<float4*>(out + (size_t)k * N);
        ok[g] = o;
    }
}

extern "C" void kernel_launch(void* const* d_in, const int* in_sizes, int n_in,
                              void* d_out, int out_size, void* d_ws, size_t ws_size,
                              hipStream_t stream) {
    const float* x = (const float*)d_in[0];   // [N, 4]
    const float* W = (const float*)d_in[1];   // [32, 1, 4]
    const float* b = (const float*)d_in[2];   // [32, 1]
    float* out = (float*)d_out;               // [32, N, 1]

    const int N  = in_sizes[0] / D;           // 2,000,000
    const int n4 = N / 4;                     // 500,000 (N divisible by 4)

    const int block = 256;
    const int grid  = (n4 + block - 1) / block;
    bignet_kernel<<<grid, block, 0, stream>>>(x, W, b, out, n4, N);
}

// Round 2
// 280.233 us; speedup vs baseline: 1.0130x; 1.0130x over previous
//
#include <hip/hip_runtime.h>

// out[k, n] = dot(x[n, 0:4], W[k, 0:4]) + b[k],  k in [0,32), n = 2e6.
// Memory-bound: 256 MB write + 32 MB read. R2: restructure so each block
// writes only KB=8 output streams (was 32) and use nontemporal stores so
// the 256 MB output doesn't thrash L2; x stays cached for the 4x re-read.

constexpr int K  = 32;
constexpr int D  = 4;
constexpr int KB = 8;   // heads per block (grid.y = K/KB = 4)

typedef float f32x4 __attribute__((ext_vector_type(4)));

__global__ __launch_bounds__(256) void bignet_kernel(
    const float* __restrict__ x,
    const float* __restrict__ W,
    const float* __restrict__ b,
    float* __restrict__ out,
    int n4,        // number of 4-row groups (N/4)
    int N)         // total rows
{
    const int g = blockIdx.x * blockDim.x + threadIdx.x;
    if (g >= n4) return;
    const int k0 = blockIdx.y * KB;

    // 4 consecutive rows of x: 64 contiguous bytes per thread (cached loads).
    const f32x4* x4 = reinterpret_cast<const f32x4*>(x);
    const f32x4 x0 = x4[(size_t)g * 4 + 0];
    const f32x4 x1 = x4[(size_t)g * 4 + 1];
    const f32x4 x2 = x4[(size_t)g * 4 + 2];
    const f32x4 x3 = x4[(size_t)g * 4 + 3];

    const f32x4* W4 = reinterpret_cast<const f32x4*>(W);

    #pragma unroll
    for (int kk = 0; kk < KB; ++kk) {
        const int k = k0 + kk;
        const f32x4 w = W4[k];       // block-uniform -> scalar loads
        const float bk = b[k];

        f32x4 o;
        o.x = fmaf(x0.x, w.x, fmaf(x0.y, w.y, fmaf(x0.z, w.z, fmaf(x0.w, w.w, bk))));
        o.y = fmaf(x1.x, w.x, fmaf(x1.y, w.y, fmaf(x1.z, w.z, fmaf(x1.w, w.w, bk))));
        o.z = fmaf(x2.x, w.x, fmaf(x2.y, w.y, fmaf(x2.z, w.z, fmaf(x2.w, w.w, bk))));
        o.w = fmaf(x3.x, w.x, fmaf(x3.y, w.y, fmaf(x3.z, w.z, fmaf(x3.w, w.w, bk))));

        // out + k*N is 16B-aligned (k*8,000,000 B). One coalesced 1KB/wave
        // nontemporal stream store per head.
        f32x4* ok = reinterpret_cast<f32x4*>(out + (size_t)k * N);
        __builtin_nontemporal_store(o, ok + g);
    }
}

extern "C" void kernel_launch(void* const* d_in, const int* in_sizes, int n_in,
                              void* d_out, int out_size, void* d_ws, size_t ws_size,
                              hipStream_t stream) {
    const float* x = (const float*)d_in[0];   // [N, 4]
    const float* W = (const float*)d_in[1];   // [32, 1, 4]
    const float* b = (const float*)d_in[2];   // [32, 1]
    float* out = (float*)d_out;               // [32, N, 1]

    const int N  = in_sizes[0] / D;           // 2,000,000
    const int n4 = N / 4;                     // 500,000

    const int block = 256;
    dim3 grid((n4 + block - 1) / block, K / KB);
    bignet_kernel<<<grid, block, 0, stream>>>(x, W, b, out, n4, N);
}